// Round 1
// baseline (324.107 us; speedup 1.0000x reference)
//
#include <hip/hip_runtime.h>
#include <math.h>

#define NN 4096
#define PP 10
#define DD 17
#define DIM 300
#define NPD (NN * PP * DD)

__global__ __launch_bounds__(256) void hs_fwd_kernel(
    const int* __restrict__ word_idx,   // [N]
    const int* __restrict__ paths,      // [N,P,D]
    const int* __restrict__ labels,     // [N,P,D]
    const float* __restrict__ emb1,     // [VOCAB, DIM]
    const float* __restrict__ emb2,     // [VOCAB-1, DIM]
    float* __restrict__ out,            // [N*P*D]
    float* __restrict__ target)         // [N*P*D]
{
    const int wave = (int)((blockIdx.x * blockDim.x + threadIdx.x) >> 6);
    const int lane = (int)(threadIdx.x & 63);
    if (wave >= NN * PP) return;
    const int n = wave / PP;

    // proj[n] strided across lanes: lane holds elements lane, lane+64, ..., lane+256
    const float* e1 = emb1 + (long long)word_idx[n] * DIM;
    const float pr0 = e1[lane];
    const float pr1 = e1[lane + 64];
    const float pr2 = e1[lane + 128];
    const float pr3 = e1[lane + 192];
    const float pr4 = (lane < DIM - 256) ? e1[lane + 256] : 0.0f;

    const long long base = (long long)wave * DD;
    const int my_path  = (lane < DD) ? paths[base + lane]  : 0;
    const int my_label = (lane < DD) ? labels[base + lane] : 0;

    float my_logit = 0.0f;
    #pragma unroll
    for (int k = 0; k < DD; ++k) {
        const int row = __shfl(my_path, k);
        const float* e2 = emb2 + (long long)row * DIM;
        float acc = pr0 * e2[lane]
                  + pr1 * e2[lane + 64]
                  + pr2 * e2[lane + 128]
                  + pr3 * e2[lane + 192];
        if (lane < DIM - 256) acc += pr4 * e2[lane + 256];
        // butterfly reduction across the 64-lane wave
        #pragma unroll
        for (int off = 32; off > 0; off >>= 1)
            acc += __shfl_xor(acc, off);
        if (lane == k) my_logit = acc;
    }

    if (lane < DD) {
        const float o = 1.0f / (1.0f + expf(-my_logit));
        out[base + lane] = o;
        const int mask = (o >= 0.5f) ? 1 : 0;
        target[base + lane] = (mask == my_label) ? 1.0f : 0.0f;
    }
}

extern "C" void kernel_launch(void* const* d_in, const int* in_sizes, int n_in,
                              void* d_out, int out_size, void* d_ws, size_t ws_size,
                              hipStream_t stream) {
    const int*   word_idx = (const int*)d_in[0];
    const int*   paths    = (const int*)d_in[1];
    const int*   labels   = (const int*)d_in[2];
    const float* emb1     = (const float*)d_in[3];
    const float* emb2     = (const float*)d_in[4];

    float* out    = (float*)d_out;          // [N*P*D] sigmoid outputs
    float* target = (float*)d_out + NPD;    // [N*P*D] targets

    const int total_waves = NN * PP;              // one wave per (n,p)
    const int waves_per_block = 4;                // 256 threads
    const int blocks = (total_waves + waves_per_block - 1) / waves_per_block;

    hs_fwd_kernel<<<blocks, 256, 0, stream>>>(word_idx, paths, labels, emb1, emb2, out, target);
}

// Round 2
// 322.939 us; speedup vs baseline: 1.0036x; 1.0036x over previous
//
#include <hip/hip_runtime.h>
#include <math.h>

#define NN 4096
#define PP 10
#define DD 17
#define DIM 300
#define NPD (NN * PP * DD)

__global__ __launch_bounds__(256) void hs_fwd_kernel(
    const int* __restrict__ word_idx,   // [N]
    const int* __restrict__ paths,      // [N,P,D]
    const int* __restrict__ labels,     // [N,P,D]
    const float* __restrict__ emb1,     // [VOCAB, DIM]
    const float* __restrict__ emb2,     // [VOCAB-1, DIM]
    float* __restrict__ out,            // [N*P*D]
    float* __restrict__ target)         // [N*P*D]
{
    const int wave = (int)((blockIdx.x * blockDim.x + threadIdx.x) >> 6);
    const int lane = (int)(threadIdx.x & 63);
    if (wave >= NN * PP) return;
    const int n = wave / PP;
    const int j    = lane & 31;   // lane within half-wave
    const int half = lane >> 5;   // which half-wave (0/1)

    // proj[n] as float4 strided across the 32 lanes of each half-wave.
    // Rows are 1200 B (75 float4), 16B-aligned (1200 % 16 == 0).
    const float4* p4 = (const float4*)(emb1 + (long long)word_idx[n] * DIM);
    const float4 pr0 = p4[j];
    const float4 pr1 = p4[j + 32];
    const float4 pr2 = (j < 11) ? p4[j + 64] : make_float4(0.f, 0.f, 0.f, 0.f);

    const long long base = (long long)wave * DD;
    const int my_path  = (lane < DD) ? paths[base + lane]  : 0;
    const int my_label = (lane < DD) ? labels[base + lane] : 0;

    float my_logit = 0.0f;

    #pragma unroll
    for (int i = 0; i < 9; ++i) {
        const int k = 2 * i + half;     // row handled by this half-wave
        float acc = 0.0f;
        if (k < DD) {
            const int row = __shfl(my_path, k);
            const float4* r4 = (const float4*)(emb2 + (long long)row * DIM);
            const float4 a0 = r4[j];
            const float4 a1 = r4[j + 32];
            acc = pr0.x * a0.x + pr0.y * a0.y + pr0.z * a0.z + pr0.w * a0.w
                + pr1.x * a1.x + pr1.y * a1.y + pr1.z * a1.z + pr1.w * a1.w;
            if (j < 11) {
                const float4 a2 = r4[j + 64];
                acc += pr2.x * a2.x + pr2.y * a2.y + pr2.z * a2.z + pr2.w * a2.w;
            }
        }
        // butterfly within each 32-lane half
        #pragma unroll
        for (int off = 16; off > 0; off >>= 1)
            acc += __shfl_xor(acc, off);
        // exchange: half-0 lanes see half-1's row sum in `other`
        const float other = __shfl_xor(acc, 32);
        if (lane == 2 * i) my_logit = acc;                       // even row k=2i
        if (2 * i + 1 < DD && lane == 2 * i + 1) my_logit = other; // odd row k=2i+1
    }

    if (lane < DD) {
        const float o = 1.0f / (1.0f + expf(-my_logit));
        out[base + lane] = o;
        const int mask = (o >= 0.5f) ? 1 : 0;
        target[base + lane] = (mask == my_label) ? 1.0f : 0.0f;
    }
}

extern "C" void kernel_launch(void* const* d_in, const int* in_sizes, int n_in,
                              void* d_out, int out_size, void* d_ws, size_t ws_size,
                              hipStream_t stream) {
    const int*   word_idx = (const int*)d_in[0];
    const int*   paths    = (const int*)d_in[1];
    const int*   labels   = (const int*)d_in[2];
    const float* emb1     = (const float*)d_in[3];
    const float* emb2     = (const float*)d_in[4];

    float* out    = (float*)d_out;          // [N*P*D] sigmoid outputs
    float* target = (float*)d_out + NPD;    // [N*P*D] targets

    const int total_waves = NN * PP;        // one wave per (n,p)
    const int waves_per_block = 4;          // 256 threads
    const int blocks = (total_waves + waves_per_block - 1) / waves_per_block;

    hs_fwd_kernel<<<blocks, 256, 0, stream>>>(word_idx, paths, labels, emb1, emb2, out, target);
}